// Round 7
// baseline (465.731 us; speedup 1.0000x reference)
//
#include <hip/hip_runtime.h>
#include <hip/hip_fp16.h>

#define IN_DIM 512
#define OUT_DIM 16
#define KC 32
#define TILE_ROWS 256

#define BSHIFT 8                 // 256 nodes per bucket
#define BNODES 256
#define MAXBUCK 512              // supports n <= 131072
#define BCOUNT_CHUNK 4096        // edges per bcount block
#define BIN_CHUNK 4096           // edges per binning block (16/thread, round-4 proven)

// ---------------------------------------------------------------------------
// hp(fp16) = rsqrt(deg) ⊙ (x @ W), no-LDS row-streaming GEMM.
// Thread (r, q): lane owns row rbase+r, K-segment q (128 floats), read as 32
// sequential float4 (lane-sequential -> full 64B-line use via L1/L2).
// k is wave-uniform (q = tid>>6) -> W stays on the scalar s_load path.
// NO barriers in the main loop: 8-deep double-buffered loads + TLP hide HBM.
// One barrier for the 4-way cross-segment reduce at the end.
// ---------------------------------------------------------------------------
__global__ __launch_bounds__(256, 4) void gemm_rows(const float* __restrict__ x,
                                                    const float* __restrict__ W,
                                                    const int* __restrict__ hist,
                                                    __half* __restrict__ hp, int n) {
    __shared__ float red[3 * 64 * 17];            // 13 KB: 3 segs x 64 rows x 17
    const int tid = threadIdx.x;
    const int r = tid & 63;
    const int q = __builtin_amdgcn_readfirstlane(tid >> 6);  // wave-uniform seg
    const int rbase = blockIdx.x * 64;
    const int myrow = rbase + r;
    const bool ok = myrow < n;

    float acc[OUT_DIM];
#pragma unroll
    for (int j = 0; j < OUT_DIM; ++j) acc[j] = 0.f;

    const float* xr = x + (size_t)myrow * IN_DIM + q * 128;
    const float* Wq = W + (size_t)q * 128 * OUT_DIM;

    float4 fA[8], fB[8];
    if (ok) {
#pragma unroll
        for (int i = 0; i < 8; ++i) fA[i] = *(const float4*)(xr + i * 4);
    }

#pragma unroll
    for (int g = 0; g < 4; ++g) {                 // 4 groups of 8 float4 = 128 floats
        // issue next group into the other buffer (static indices, rule #20)
        if (ok && g < 3) {
            if ((g & 1) == 0) {
#pragma unroll
                for (int i = 0; i < 8; ++i) fB[i] = *(const float4*)(xr + (g + 1) * 32 + i * 4);
            } else {
#pragma unroll
                for (int i = 0; i < 8; ++i) fA[i] = *(const float4*)(xr + (g + 1) * 32 + i * 4);
            }
        }
        // consume current group
#pragma unroll
        for (int i = 0; i < 8; ++i) {
            const float4 f = ((g & 1) == 0) ? fA[i] : fB[i];
            const float* wr = Wq + (size_t)(g * 32 + i * 4) * OUT_DIM;  // uniform -> s_load
#pragma unroll
            for (int j = 0; j < 4; ++j) {
                const float xv = (j == 0) ? f.x : (j == 1) ? f.y : (j == 2) ? f.z : f.w;
                const float* w = wr + j * OUT_DIM;
                const float4 w0 = *(const float4*)(w + 0);
                const float4 w1 = *(const float4*)(w + 4);
                const float4 w2 = *(const float4*)(w + 8);
                const float4 w3 = *(const float4*)(w + 12);
                acc[0]  += xv * w0.x; acc[1]  += xv * w0.y; acc[2]  += xv * w0.z; acc[3]  += xv * w0.w;
                acc[4]  += xv * w1.x; acc[5]  += xv * w1.y; acc[6]  += xv * w1.z; acc[7]  += xv * w1.w;
                acc[8]  += xv * w2.x; acc[9]  += xv * w2.y; acc[10] += xv * w2.z; acc[11] += xv * w2.w;
                acc[12] += xv * w3.x; acc[13] += xv * w3.y; acc[14] += xv * w3.z; acc[15] += xv * w3.w;
            }
        }
    }

    // cross-segment reduce: segs 1..3 park partials in LDS (stride 17), seg 0 sums
    if (q > 0) {
        float* d = red + (q - 1) * (64 * 17) + r * 17;
#pragma unroll
        for (int j = 0; j < OUT_DIM; ++j) d[j] = acc[j];
    }
    __syncthreads();
    if (tid < 64 && myrow < n) {
        const float* p0 = red + 0 * (64 * 17) + tid * 17;
        const float* p1 = red + 1 * (64 * 17) + tid * 17;
        const float* p2 = red + 2 * (64 * 17) + tid * 17;
        const float s = rsqrtf((float)(hist[myrow] + 1));
        __half2* op = (__half2*)(hp + (size_t)myrow * OUT_DIM);
#pragma unroll
        for (int j = 0; j < 8; ++j) {
            const float lo = acc[2 * j]     + p0[2 * j]     + p1[2 * j]     + p2[2 * j];
            const float hi = acc[2 * j + 1] + p0[2 * j + 1] + p1[2 * j + 1] + p2[2 * j + 1];
            op[j] = __floats2half2_rn(s * lo, s * hi);
        }
    }
}

// ---------------------------------------------------------------------------
// fallback-path GEMM (proven): 256 rows/block, full K per thread
// ---------------------------------------------------------------------------
__global__ __launch_bounds__(256) void gemm_xw(const float* __restrict__ x,
                                               const float* __restrict__ W,
                                               const int* __restrict__ hist,
                                               __half* __restrict__ hp, int n) {
    __shared__ float xs[TILE_ROWS * (KC + 1)];
    const int tid = threadIdx.x;
    const int rbase = blockIdx.x * TILE_ROWS;
    const int myrow = rbase + tid;

    float acc[OUT_DIM];
#pragma unroll
    for (int j = 0; j < OUT_DIM; ++j) acc[j] = 0.f;

    for (int kc = 0; kc < IN_DIM; kc += KC) {
        __syncthreads();
#pragma unroll
        for (int i = 0; i < 8; ++i) {
            const int v = tid + 256 * i;
            const int r = v >> 3;
            const int c = (v & 7) << 2;
            if (rbase + r < n) {
                const float4 f = *(const float4*)(x + (size_t)(rbase + r) * IN_DIM + kc + c);
                float* d = xs + r * (KC + 1) + c;
                d[0] = f.x; d[1] = f.y; d[2] = f.z; d[3] = f.w;
            }
        }
        __syncthreads();

        const float* xrow = xs + tid * (KC + 1);
#pragma unroll 4
        for (int k = 0; k < KC; ++k) {
            const float xv = xrow[k];
            const float* wr = W + (size_t)(kc + k) * OUT_DIM;
            const float4 w0 = *(const float4*)(wr + 0);
            const float4 w1 = *(const float4*)(wr + 4);
            const float4 w2 = *(const float4*)(wr + 8);
            const float4 w3 = *(const float4*)(wr + 12);
            acc[0]  += xv * w0.x; acc[1]  += xv * w0.y; acc[2]  += xv * w0.z; acc[3]  += xv * w0.w;
            acc[4]  += xv * w1.x; acc[5]  += xv * w1.y; acc[6]  += xv * w1.z; acc[7]  += xv * w1.w;
            acc[8]  += xv * w2.x; acc[9]  += xv * w2.y; acc[10] += xv * w2.z; acc[11] += xv * w2.w;
            acc[12] += xv * w3.x; acc[13] += xv * w3.y; acc[14] += xv * w3.z; acc[15] += xv * w3.w;
        }
    }

    if (myrow < n) {
        const float s = rsqrtf((float)(hist[myrow] + 1));
        __half2* op = (__half2*)(hp + (size_t)myrow * OUT_DIM);
#pragma unroll
        for (int j = 0; j < 8; ++j)
            op[j] = __floats2half2_rn(s * acc[2 * j], s * acc[2 * j + 1]);
    }
}

// ---------------------------------------------------------------------------
// wave-0 exclusive scans over LDS arrays (lane-private spans -> shfl scan)
// ---------------------------------------------------------------------------
__device__ inline void scan512_excl(const int* src, int* dst, int lane) {
    int c[8], pre[8];
    int tot = 0;
#pragma unroll
    for (int k = 0; k < 8; ++k) { c[k] = src[lane * 8 + k]; pre[k] = tot; tot += c[k]; }
    int incl = tot;
#pragma unroll
    for (int d = 1; d < 64; d <<= 1) {
        const int u = __shfl_up(incl, d);
        if (lane >= d) incl += u;
    }
    const int excl = incl - tot;
#pragma unroll
    for (int k = 0; k < 8; ++k) dst[lane * 8 + k] = excl + pre[k];
}

__device__ inline void scan256_excl(const int* src, int* dst, int lane) {
    int c[4], pre[4];
    int tot = 0;
#pragma unroll
    for (int k = 0; k < 4; ++k) { c[k] = src[lane * 4 + k]; pre[k] = tot; tot += c[k]; }
    int incl = tot;
#pragma unroll
    for (int d = 1; d < 64; d <<= 1) {
        const int u = __shfl_up(incl, d);
        if (lane >= d) incl += u;
    }
    const int excl = incl - tot;
#pragma unroll
    for (int k = 0; k < 4; ++k) dst[lane * 4 + k] = excl + pre[k];
}

// ---------------------------------------------------------------------------
// per-bucket edge counts: LDS histogram per block, one global atomic/bucket
// ---------------------------------------------------------------------------
__global__ __launch_bounds__(256) void bcount(const int* __restrict__ dst,
                                              int* __restrict__ bcnt, int E, int nbuck) {
    __shared__ int lhist[MAXBUCK];
    const int tid = threadIdx.x;
    for (int i = tid; i < MAXBUCK; i += 256) lhist[i] = 0;
    __syncthreads();

    const int base = blockIdx.x * BCOUNT_CHUNK + tid * 16;
#pragma unroll
    for (int g = 0; g < 4; ++g) {
        const int e = base + g * 4;
        if (e + 3 < E) {
            const int4 d = *(const int4*)(dst + e);
            atomicAdd(&lhist[d.x >> BSHIFT], 1);
            atomicAdd(&lhist[d.y >> BSHIFT], 1);
            atomicAdd(&lhist[d.z >> BSHIFT], 1);
            atomicAdd(&lhist[d.w >> BSHIFT], 1);
        } else {
            for (int u = 0; u < 4; ++u)
                if (e + u < E) atomicAdd(&lhist[dst[e + u] >> BSHIFT], 1);
        }
    }
    __syncthreads();
    for (int i = tid; i < nbuck; i += 256)
        if (lhist[i] > 0) atomicAdd(&bcnt[i], lhist[i]);
}

// exclusive scan of bucket counts -> segment base + write cursor
__global__ __launch_bounds__(512) void bucket_scan(const int* __restrict__ bcnt,
                                                   int* __restrict__ bbase,
                                                   int* __restrict__ bcur, int nbuck) {
    __shared__ int sm[MAXBUCK];
    const int t = threadIdx.x;
    sm[t] = (t < nbuck) ? bcnt[t] : 0;
    __syncthreads();
    if (t < 64) scan512_excl(sm, sm, t);
    __syncthreads();
    bbase[t] = sm[t];
    bcur[t] = sm[t];
}

// ---------------------------------------------------------------------------
// bin edges by dst bucket (256 nodes/bucket), LDS-staged for coalesced output.
// bins[pos] = (src << 8) | (dst & 255), bucket-contiguous.  [round-4 proven]
// ---------------------------------------------------------------------------
__global__ __launch_bounds__(256) void bin_edges(const int* __restrict__ ei,
                                                 int* __restrict__ bcur,
                                                 int* __restrict__ bins,
                                                 int E, int nbuck) {
    __shared__ int lhist[MAXBUCK];
    __shared__ int lbase[MAXBUCK];
    __shared__ int gbase[MAXBUCK];
    __shared__ int stage[BIN_CHUNK];
    __shared__ short sbkt[BIN_CHUNK];

    const int tid = threadIdx.x;
    const int e0 = blockIdx.x * BIN_CHUNK;
    const int cnt = min(BIN_CHUNK, E - e0);

    for (int i = tid; i < MAXBUCK; i += 256) lhist[i] = 0;
    __syncthreads();

    int myb[16], myr[16], myp[16];
    const int base = e0 + tid * 16;
#pragma unroll
    for (int g = 0; g < 4; ++g) {
        const int e = base + g * 4;
        int ss[4], dd[4];
        if ((E & 3) == 0 && e + 3 < E) {
            const int4 s4 = *(const int4*)(ei + e);
            const int4 d4 = *(const int4*)(ei + (size_t)E + e);
            ss[0] = s4.x; ss[1] = s4.y; ss[2] = s4.z; ss[3] = s4.w;
            dd[0] = d4.x; dd[1] = d4.y; dd[2] = d4.z; dd[3] = d4.w;
        } else {
#pragma unroll
            for (int u = 0; u < 4; ++u) {
                const int idx = e + u;
                ss[u] = (idx < E) ? ei[idx] : -1;
                dd[u] = (idx < E) ? ei[(size_t)E + idx] : 0;
            }
        }
#pragma unroll
        for (int u = 0; u < 4; ++u) {
            const int j = g * 4 + u;
            if (ss[u] >= 0) {
                const int bk = dd[u] >> BSHIFT;
                myb[j] = bk;
                myp[j] = (ss[u] << BSHIFT) | (dd[u] & (BNODES - 1));
                myr[j] = atomicAdd(&lhist[bk], 1);
            } else {
                myb[j] = -1; myr[j] = 0; myp[j] = 0;
            }
        }
    }
    __syncthreads();

    if (tid < 64) scan512_excl(lhist, lbase, tid);     // counts -> local offsets
    for (int i = tid; i < nbuck; i += 256)
        if (lhist[i] > 0) gbase[i] = atomicAdd(&bcur[i], lhist[i]);
    __syncthreads();

#pragma unroll
    for (int j = 0; j < 16; ++j) {
        if (myb[j] >= 0) {
            const int p = lbase[myb[j]] + myr[j];
            stage[p] = myp[j];
            sbkt[p] = (short)myb[j];
        }
    }
    __syncthreads();

    for (int i = tid; i < cnt; i += 256) {
        const int bk = sbkt[i];
        bins[gbase[bk] + (i - lbase[bk])] = stage[i];
    }
}

// ---------------------------------------------------------------------------
// per-bucket counting sort -> node-sorted csr. Random 4B writes confined to
// this bucket's private ~32KB window => L2-absorbed, single writeback.
// Also emits per-node degree (hist) and segment offset (off) for free.
// ---------------------------------------------------------------------------
__global__ __launch_bounds__(256) void bucket_sort(const int* __restrict__ bins,
                                                   const int* __restrict__ bbase,
                                                   const int* __restrict__ bcur,
                                                   int* __restrict__ csr,
                                                   int* __restrict__ hist,
                                                   int* __restrict__ off, int n) {
    __shared__ int nhist[BNODES];
    __shared__ int nbase[BNODES];
    __shared__ int ncur[BNODES];
    const int tid = threadIdx.x;
    const int b = blockIdx.x;
    const int s = bbase[b];
    const int e = bcur[b];

    nhist[tid] = 0;
    __syncthreads();
    for (int i = s + tid; i < e; i += 256)
        atomicAdd(&nhist[bins[i] & (BNODES - 1)], 1);
    __syncthreads();
    if (tid < 64) scan256_excl(nhist, nbase, tid);
    __syncthreads();

    const int node = (b << BSHIFT) + tid;
    if (node < n) {
        hist[node] = nhist[tid];
        off[node] = s + nbase[tid];
    }
    ncur[tid] = nbase[tid];
    __syncthreads();

    for (int i = s + tid; i < e; i += 256) {
        const int p = bins[i];                       // L2 hit (2nd read)
        const int r = atomicAdd(&ncur[p & (BNODES - 1)], 1);
        csr[s + r] = p >> BSHIFT;
    }
}

// ---------------------------------------------------------------------------
// per dst node: 8 lanes (one __half2 feature pair each) walk the CSR segment,
// gather hp[src] (L2-resident table), accumulate fp32, finalize + bias + out.
// [proven round 3: ~30us]
// ---------------------------------------------------------------------------
__global__ __launch_bounds__(256) void gather_out(const int* __restrict__ csr,
                                                  const int* __restrict__ off,
                                                  const int* __restrict__ hist,
                                                  const __half* __restrict__ hp,
                                                  const float* __restrict__ b,
                                                  float* __restrict__ out, int n) {
    const long long gid = (long long)blockIdx.x * 256 + threadIdx.x;
    const int d = (int)(gid >> 3);
    const int j2 = (int)(gid & 7);
    if (d >= n) return;

    const int base = off[d];
    const int deg = hist[d];
    const __half2* hpt = (const __half2*)hp;

    // self-loop contribution
    const __half2 sv = hpt[(size_t)d * 8 + j2];
    float ax = __low2float(sv), ay = __high2float(sv);

    int k = 0;
    for (; k + 4 <= deg; k += 4) {      // 4 independent gathers in flight
        const int s0 = csr[base + k + 0];
        const int s1 = csr[base + k + 1];
        const int s2 = csr[base + k + 2];
        const int s3 = csr[base + k + 3];
        const __half2 v0 = hpt[(size_t)s0 * 8 + j2];
        const __half2 v1 = hpt[(size_t)s1 * 8 + j2];
        const __half2 v2 = hpt[(size_t)s2 * 8 + j2];
        const __half2 v3 = hpt[(size_t)s3 * 8 + j2];
        ax += __low2float(v0) + __low2float(v1) + __low2float(v2) + __low2float(v3);
        ay += __high2float(v0) + __high2float(v1) + __high2float(v2) + __high2float(v3);
    }
    for (; k < deg; ++k) {
        const __half2 v = hpt[(size_t)csr[base + k] * 8 + j2];
        ax += __low2float(v);
        ay += __high2float(v);
    }

    const float di = rsqrtf((float)(deg + 1));
    float2 o;
    o.x = di * ax + b[2 * j2];
    o.y = di * ay + b[2 * j2 + 1];
    ((float2*)out)[(size_t)d * 8 + j2] = o;
}

// ---------------------------------------------------------------------------
// fallback path (proven atomic scatter) — only if guards fail
// ---------------------------------------------------------------------------
__global__ void hist_dst(const int* __restrict__ dst, int* __restrict__ hist, int E) {
    const int t = blockIdx.x * 256 + threadIdx.x;
    const int e0 = t * 4;
    if ((E & 3) == 0 && e0 + 3 < E) {
        const int4 d = *(const int4*)(dst + e0);
        atomicAdd(&hist[d.x], 1);
        atomicAdd(&hist[d.y], 1);
        atomicAdd(&hist[d.z], 1);
        atomicAdd(&hist[d.w], 1);
    } else {
        for (int e = e0; e < E && e < e0 + 4; ++e) atomicAdd(&hist[dst[e]], 1);
    }
}

__global__ __launch_bounds__(256) void scatter_f16(const int* __restrict__ ei,
                                                   const __half* __restrict__ hp,
                                                   __half2* __restrict__ acc, int E) {
    const long long gid = (long long)blockIdx.x * 256 + threadIdx.x;
    const int g = (int)(gid >> 3);
    const int j2 = (int)(gid & 7);
    const int e0 = g * 4;
    if (e0 >= E) return;

    int src[4], dst[4];
#pragma unroll
    for (int u = 0; u < 4; ++u) {
        const int e = e0 + u;
        src[u] = (e < E) ? ei[e] : -1;
        dst[u] = (e < E) ? ei[(size_t)E + e] : -1;
    }
    __half2 v[4];
#pragma unroll
    for (int u = 0; u < 4; ++u)
        if (src[u] >= 0) v[u] = ((const __half2*)(hp + (size_t)src[u] * OUT_DIM))[j2];
#pragma unroll
    for (int u = 0; u < 4; ++u)
        if (dst[u] >= 0) unsafeAtomicAdd(&acc[(size_t)dst[u] * 8 + j2], v[u]);
}

__global__ void finalize(const __half* __restrict__ acc, const __half* __restrict__ hp,
                         const int* __restrict__ hist, const float* __restrict__ b,
                         float* __restrict__ out, int n) {
    const int gid = blockIdx.x * 256 + threadIdx.x;
    if (gid >= n * OUT_DIM) return;
    const int i = gid >> 4;
    const int j = gid & 15;
    const float di = rsqrtf((float)(hist[i] + 1));
    out[gid] = di * (__half2float(acc[gid]) + __half2float(hp[gid])) + b[j];
}

// ---------------------------------------------------------------------------

extern "C" void kernel_launch(void* const* d_in, const int* in_sizes, int n_in,
                              void* d_out, int out_size, void* d_ws, size_t ws_size,
                              hipStream_t stream) {
    const float* x  = (const float*)d_in[0];
    const int*   ei = (const int*)d_in[1];   // int inputs delivered as int32
    const float* W  = (const float*)d_in[2];
    const float* b  = (const float*)d_in[3];
    float* out = (float*)d_out;

    const int n = in_sizes[0] / IN_DIM;   // 100000
    const int E = in_sizes[1] / 2;        // 3200000
    const int nbuck = (n + BNODES - 1) >> BSHIFT;

    // fast-path ws layout:
    // hp [n*16 f16] | hist [n] | off [n] | bbase[512] | bcur[512] | bcnt[512]
    // | bins [E] | csr [E]
    __half* hp    = (__half*)d_ws;
    int*    hist  = (int*)(hp + (size_t)n * OUT_DIM);
    int*    off   = hist + n;
    int*    bbase = off + n;
    int*    bcur  = bbase + MAXBUCK;
    int*    bcnt  = bcur + MAXBUCK;
    int*    bins  = bcnt + MAXBUCK;
    int*    csr   = bins + (size_t)E;

    const size_t need = (size_t)n * OUT_DIM * sizeof(__half)
                      + ((size_t)2 * n + 3 * MAXBUCK) * sizeof(int)
                      + 2 * (size_t)E * sizeof(int);

    if (ws_size >= need && nbuck <= MAXBUCK && n < (1 << 23)) {
        hipMemsetAsync(bcnt, 0, MAXBUCK * sizeof(int), stream);

        bcount<<<(E + BCOUNT_CHUNK - 1) / BCOUNT_CHUNK, 256, 0, stream>>>(ei + E, bcnt, E, nbuck);
        bucket_scan<<<1, 512, 0, stream>>>(bcnt, bbase, bcur, nbuck);
        bin_edges<<<(E + BIN_CHUNK - 1) / BIN_CHUNK, 256, 0, stream>>>(ei, bcur, bins, E, nbuck);
        bucket_sort<<<nbuck, 256, 0, stream>>>(bins, bbase, bcur, csr, hist, off, n);
        gemm_rows<<<(n + 63) / 64, 256, 0, stream>>>(x, W, hist, hp, n);
        gather_out<<<(int)(((size_t)n * 8 + 255) / 256), 256, 0, stream>>>(csr, off, hist, hp, b, out, n);
    } else {
        // fallback: proven atomic-scatter path (~7.2 MB ws)
        __half* acc = (__half*)(hist + n);
        hipMemsetAsync(hist, 0, (size_t)n * sizeof(int), stream);
        hipMemsetAsync(acc, 0, (size_t)n * OUT_DIM * sizeof(__half), stream);

        hist_dst<<<(E + 1023) / 1024, 256, 0, stream>>>(ei + E, hist, E);
        gemm_xw<<<(n + TILE_ROWS - 1) / TILE_ROWS, 256, 0, stream>>>(x, W, hist, hp, n);
        const long long st = ((long long)(E + 3) / 4) * 8;
        scatter_f16<<<(int)((st + 255) / 256), 256, 0, stream>>>(ei, hp, (__half2*)acc, E);
        finalize<<<(n * OUT_DIM + 255) / 256, 256, 0, stream>>>(acc, hp, hist, b, out, n);
    }
}

// Round 9
// 428.265 us; speedup vs baseline: 1.0875x; 1.0875x over previous
//
#include <hip/hip_runtime.h>
#include <hip/hip_fp16.h>

#define IN_DIM 512
#define OUT_DIM 16
#define KC 32
#define TILE_ROWS 256

#define BSHIFT 8                 // 256 nodes per bucket
#define BNODES 256
#define MAXBUCK 512              // supports n <= 131072
#define BCOUNT_CHUNK 4096        // edges per bcount block
#define BIN_CHUNK 4096           // edges per binning block (16/thread, round-4 proven)

// ---------------------------------------------------------------------------
// hp(fp16) = rsqrt(deg) ⊙ (x @ W) — BARRIER-FREE wave-private GEMM.
// Each wave owns 64 rows + a private LDS slice (64 x 33 floats). Per K-chunk
// (KC=32): write staged regs -> own LDS, issue next chunk's 8 float4 loads,
// compute current chunk (32 ds_read + 512 FMA hides ~900cy HBM latency).
// Only wave-local lgkmcnt/vmcnt ordering — NO __syncthreads anywhere, no
// cross-wave coupling (fixes the 2-phase barrier-drain stall: 205MB @1.8TB/s).
// Lane owns a full row (K=512) -> no reduce. k wave-uniform -> W via s_load.
// LDS 33.8KB/block -> 4 blocks = 16 waves/CU, each independently streaming.
// ---------------------------------------------------------------------------
__global__ __launch_bounds__(256) void gemm_wave(const float* __restrict__ x,
                                                 const float* __restrict__ W,
                                                 const int* __restrict__ hist,
                                                 __half* __restrict__ hp, int n) {
    __shared__ float xs[4 * 64 * (KC + 1)];       // 4 wave-private slices
    const int tid = threadIdx.x;
    const int lane = tid & 63;
    const int wid = __builtin_amdgcn_readfirstlane(tid >> 6);
    const int rbase = blockIdx.x * 256 + wid * 64;
    if (rbase >= n) return;                        // whole wave idle (no barriers!)
    const int myrow = rbase + lane;

    float* xw = xs + wid * (64 * (KC + 1));        // this wave's slice
    // staging geometry: iter i, lane l -> row 8i+(l>>3), col4 (l&7)*4
    const int srow = lane >> 3;
    const int scol = (lane & 7) << 2;

    float4 stA[8], stB[8];

#define LOADC(buf, c)                                                          \
    {                                                                          \
        _Pragma("unroll")                                                      \
        for (int i = 0; i < 8; ++i) {                                          \
            const int rr = rbase + 8 * i + srow;                               \
            if (rr < n)                                                        \
                buf[i] = *(const float4*)(x + (size_t)rr * IN_DIM + (c) * KC + scol); \
            else                                                               \
                buf[i] = make_float4(0.f, 0.f, 0.f, 0.f);                      \
        }                                                                      \
    }

#define STOREC(buf)                                                            \
    {                                                                          \
        _Pragma("unroll")                                                      \
        for (int i = 0; i < 8; ++i) {                                          \
            float* d = xw + (8 * i + srow) * (KC + 1) + scol;                  \
            d[0] = buf[i].x; d[1] = buf[i].y; d[2] = buf[i].z; d[3] = buf[i].w; \
        }                                                                      \
    }

#define COMPUTEC(c)                                                            \
    {                                                                          \
        const float* xrow = xw + lane * (KC + 1);                              \
        const float* Wb = W + (size_t)(c) * KC * OUT_DIM;                      \
        _Pragma("unroll 4")                                                    \
        for (int k = 0; k < KC; ++k) {                                         \
            const float xv = xrow[k];                                          \
            const float* wr = Wb + k * OUT_DIM;                                \
            const float4 w0 = *(const float4*)(wr + 0);                        \
            const float4 w1 = *(const float4*)(wr + 4);                        \
            const float4 w2 = *(const float4*)(wr + 8);                        \
            const float4 w3 = *(const float4*)(wr + 12);                       \
            acc[0]  += xv * w0.x; acc[1]  += xv * w0.y; acc[2]  += xv * w0.z; acc[3]  += xv * w0.w; \
            acc[4]  += xv * w1.x; acc[5]  += xv * w1.y; acc[6]  += xv * w1.z; acc[7]  += xv * w1.w; \
            acc[8]  += xv * w2.x; acc[9]  += xv * w2.y; acc[10] += xv * w2.z; acc[11] += xv * w2.w; \
            acc[12] += xv * w3.x; acc[13] += xv * w3.y; acc[14] += xv * w3.z; acc[15] += xv * w3.w; \
        }                                                                      \
    }

    float acc[OUT_DIM];
#pragma unroll
    for (int j = 0; j < OUT_DIM; ++j) acc[j] = 0.f;

    LOADC(stA, 0);
    for (int cc = 0; cc < 8; ++cc) {              // 16 chunks, 2 per iter (static dbuf)
        const int c0 = 2 * cc, c1 = 2 * cc + 1;
        STOREC(stA);                              // vmcnt wait on stA is automatic
        LOADC(stB, c1);                           // in flight during compute(c0)
        COMPUTEC(c0);                             // lgkmcnt orders write->read
        STOREC(stB);
        if (c1 + 1 < 16) LOADC(stA, c1 + 1);
        COMPUTEC(c1);
    }

    if (myrow < n) {
        const float s = rsqrtf((float)(hist[myrow] + 1));
        __half2* op = (__half2*)(hp + (size_t)myrow * OUT_DIM);
#pragma unroll
        for (int j = 0; j < 8; ++j)
            op[j] = __floats2half2_rn(s * acc[2 * j], s * acc[2 * j + 1]);
    }
#undef LOADC
#undef STOREC
#undef COMPUTEC
}

// ---------------------------------------------------------------------------
// fallback-path GEMM (proven): 256 rows/block, full K per thread
// ---------------------------------------------------------------------------
__global__ __launch_bounds__(256) void gemm_xw(const float* __restrict__ x,
                                               const float* __restrict__ W,
                                               const int* __restrict__ hist,
                                               __half* __restrict__ hp, int n) {
    __shared__ float xs[TILE_ROWS * (KC + 1)];
    const int tid = threadIdx.x;
    const int rbase = blockIdx.x * TILE_ROWS;
    const int myrow = rbase + tid;

    float acc[OUT_DIM];
#pragma unroll
    for (int j = 0; j < OUT_DIM; ++j) acc[j] = 0.f;

    for (int kc = 0; kc < IN_DIM; kc += KC) {
        __syncthreads();
#pragma unroll
        for (int i = 0; i < 8; ++i) {
            const int v = tid + 256 * i;
            const int r = v >> 3;
            const int c = (v & 7) << 2;
            if (rbase + r < n) {
                const float4 f = *(const float4*)(x + (size_t)(rbase + r) * IN_DIM + kc + c);
                float* d = xs + r * (KC + 1) + c;
                d[0] = f.x; d[1] = f.y; d[2] = f.z; d[3] = f.w;
            }
        }
        __syncthreads();

        const float* xrow = xs + tid * (KC + 1);
#pragma unroll 4
        for (int k = 0; k < KC; ++k) {
            const float xv = xrow[k];
            const float* wr = W + (size_t)(kc + k) * OUT_DIM;
            const float4 w0 = *(const float4*)(wr + 0);
            const float4 w1 = *(const float4*)(wr + 4);
            const float4 w2 = *(const float4*)(wr + 8);
            const float4 w3 = *(const float4*)(wr + 12);
            acc[0]  += xv * w0.x; acc[1]  += xv * w0.y; acc[2]  += xv * w0.z; acc[3]  += xv * w0.w;
            acc[4]  += xv * w1.x; acc[5]  += xv * w1.y; acc[6]  += xv * w1.z; acc[7]  += xv * w1.w;
            acc[8]  += xv * w2.x; acc[9]  += xv * w2.y; acc[10] += xv * w2.z; acc[11] += xv * w2.w;
            acc[12] += xv * w3.x; acc[13] += xv * w3.y; acc[14] += xv * w3.z; acc[15] += xv * w3.w;
        }
    }

    if (myrow < n) {
        const float s = rsqrtf((float)(hist[myrow] + 1));
        __half2* op = (__half2*)(hp + (size_t)myrow * OUT_DIM);
#pragma unroll
        for (int j = 0; j < 8; ++j)
            op[j] = __floats2half2_rn(s * acc[2 * j], s * acc[2 * j + 1]);
    }
}

// ---------------------------------------------------------------------------
// wave-0 exclusive scans over LDS arrays (lane-private spans -> shfl scan)
// ---------------------------------------------------------------------------
__device__ inline void scan512_excl(const int* src, int* dst, int lane) {
    int c[8], pre[8];
    int tot = 0;
#pragma unroll
    for (int k = 0; k < 8; ++k) { c[k] = src[lane * 8 + k]; pre[k] = tot; tot += c[k]; }
    int incl = tot;
#pragma unroll
    for (int d = 1; d < 64; d <<= 1) {
        const int u = __shfl_up(incl, d);
        if (lane >= d) incl += u;
    }
    const int excl = incl - tot;
#pragma unroll
    for (int k = 0; k < 8; ++k) dst[lane * 8 + k] = excl + pre[k];
}

__device__ inline void scan256_excl(const int* src, int* dst, int lane) {
    int c[4], pre[4];
    int tot = 0;
#pragma unroll
    for (int k = 0; k < 4; ++k) { c[k] = src[lane * 4 + k]; pre[k] = tot; tot += c[k]; }
    int incl = tot;
#pragma unroll
    for (int d = 1; d < 64; d <<= 1) {
        const int u = __shfl_up(incl, d);
        if (lane >= d) incl += u;
    }
    const int excl = incl - tot;
#pragma unroll
    for (int k = 0; k < 4; ++k) dst[lane * 4 + k] = excl + pre[k];
}

// ---------------------------------------------------------------------------
// per-bucket edge counts: LDS histogram per block, one global atomic/bucket
// ---------------------------------------------------------------------------
__global__ __launch_bounds__(256) void bcount(const int* __restrict__ dst,
                                              int* __restrict__ bcnt, int E, int nbuck) {
    __shared__ int lhist[MAXBUCK];
    const int tid = threadIdx.x;
    for (int i = tid; i < MAXBUCK; i += 256) lhist[i] = 0;
    __syncthreads();

    const int base = blockIdx.x * BCOUNT_CHUNK + tid * 16;
#pragma unroll
    for (int g = 0; g < 4; ++g) {
        const int e = base + g * 4;
        if (e + 3 < E) {
            const int4 d = *(const int4*)(dst + e);
            atomicAdd(&lhist[d.x >> BSHIFT], 1);
            atomicAdd(&lhist[d.y >> BSHIFT], 1);
            atomicAdd(&lhist[d.z >> BSHIFT], 1);
            atomicAdd(&lhist[d.w >> BSHIFT], 1);
        } else {
            for (int u = 0; u < 4; ++u)
                if (e + u < E) atomicAdd(&lhist[dst[e + u] >> BSHIFT], 1);
        }
    }
    __syncthreads();
    for (int i = tid; i < nbuck; i += 256)
        if (lhist[i] > 0) atomicAdd(&bcnt[i], lhist[i]);
}

// exclusive scan of bucket counts -> segment base + write cursor
__global__ __launch_bounds__(512) void bucket_scan(const int* __restrict__ bcnt,
                                                   int* __restrict__ bbase,
                                                   int* __restrict__ bcur, int nbuck) {
    __shared__ int sm[MAXBUCK];
    const int t = threadIdx.x;
    sm[t] = (t < nbuck) ? bcnt[t] : 0;
    __syncthreads();
    if (t < 64) scan512_excl(sm, sm, t);
    __syncthreads();
    bbase[t] = sm[t];
    bcur[t] = sm[t];
}

// ---------------------------------------------------------------------------
// bin edges by dst bucket (256 nodes/bucket), LDS-staged for coalesced output.
// bins[pos] = (src << 8) | (dst & 255), bucket-contiguous.  [round-4 proven]
// ---------------------------------------------------------------------------
__global__ __launch_bounds__(256) void bin_edges(const int* __restrict__ ei,
                                                 int* __restrict__ bcur,
                                                 int* __restrict__ bins,
                                                 int E, int nbuck) {
    __shared__ int lhist[MAXBUCK];
    __shared__ int lbase[MAXBUCK];
    __shared__ int gbase[MAXBUCK];
    __shared__ int stage[BIN_CHUNK];
    __shared__ short sbkt[BIN_CHUNK];

    const int tid = threadIdx.x;
    const int e0 = blockIdx.x * BIN_CHUNK;
    const int cnt = min(BIN_CHUNK, E - e0);

    for (int i = tid; i < MAXBUCK; i += 256) lhist[i] = 0;
    __syncthreads();

    int myb[16], myr[16], myp[16];
    const int base = e0 + tid * 16;
#pragma unroll
    for (int g = 0; g < 4; ++g) {
        const int e = base + g * 4;
        int ss[4], dd[4];
        if ((E & 3) == 0 && e + 3 < E) {
            const int4 s4 = *(const int4*)(ei + e);
            const int4 d4 = *(const int4*)(ei + (size_t)E + e);
            ss[0] = s4.x; ss[1] = s4.y; ss[2] = s4.z; ss[3] = s4.w;
            dd[0] = d4.x; dd[1] = d4.y; dd[2] = d4.z; dd[3] = d4.w;
        } else {
#pragma unroll
            for (int u = 0; u < 4; ++u) {
                const int idx = e + u;
                ss[u] = (idx < E) ? ei[idx] : -1;
                dd[u] = (idx < E) ? ei[(size_t)E + idx] : 0;
            }
        }
#pragma unroll
        for (int u = 0; u < 4; ++u) {
            const int j = g * 4 + u;
            if (ss[u] >= 0) {
                const int bk = dd[u] >> BSHIFT;
                myb[j] = bk;
                myp[j] = (ss[u] << BSHIFT) | (dd[u] & (BNODES - 1));
                myr[j] = atomicAdd(&lhist[bk], 1);
            } else {
                myb[j] = -1; myr[j] = 0; myp[j] = 0;
            }
        }
    }
    __syncthreads();

    if (tid < 64) scan512_excl(lhist, lbase, tid);     // counts -> local offsets
    for (int i = tid; i < nbuck; i += 256)
        if (lhist[i] > 0) gbase[i] = atomicAdd(&bcur[i], lhist[i]);
    __syncthreads();

#pragma unroll
    for (int j = 0; j < 16; ++j) {
        if (myb[j] >= 0) {
            const int p = lbase[myb[j]] + myr[j];
            stage[p] = myp[j];
            sbkt[p] = (short)myb[j];
        }
    }
    __syncthreads();

    for (int i = tid; i < cnt; i += 256) {
        const int bk = sbkt[i];
        bins[gbase[bk] + (i - lbase[bk])] = stage[i];
    }
}

// ---------------------------------------------------------------------------
// per-bucket counting sort -> node-sorted csr. 1024 threads/block (8 serial
// iters/thread vs 32): fixes the 1.5-blocks/CU parallelism starvation.
// Random 4B writes confined to the bucket's ~32KB window => L2-absorbed.
// Also emits per-node degree (hist) and segment offset (off) for free.
// ---------------------------------------------------------------------------
__global__ __launch_bounds__(1024) void bucket_sort(const int* __restrict__ bins,
                                                    const int* __restrict__ bbase,
                                                    const int* __restrict__ bcur,
                                                    int* __restrict__ csr,
                                                    int* __restrict__ hist,
                                                    int* __restrict__ off, int n) {
    __shared__ int nhist[BNODES];
    __shared__ int nbase[BNODES];
    __shared__ int ncur[BNODES];
    const int tid = threadIdx.x;
    const int b = blockIdx.x;
    const int s = bbase[b];
    const int e = bcur[b];

    if (tid < BNODES) nhist[tid] = 0;
    __syncthreads();
    for (int i = s + tid; i < e; i += 1024)
        atomicAdd(&nhist[bins[i] & (BNODES - 1)], 1);
    __syncthreads();
    if (tid < 64) scan256_excl(nhist, nbase, tid);
    __syncthreads();

    if (tid < BNODES) {
        const int node = (b << BSHIFT) + tid;
        if (node < n) {
            hist[node] = nhist[tid];
            off[node] = s + nbase[tid];
        }
        ncur[tid] = nbase[tid];
    }
    __syncthreads();

    for (int i = s + tid; i < e; i += 1024) {
        const int p = bins[i];                       // L2 hit (2nd read)
        const int r = atomicAdd(&ncur[p & (BNODES - 1)], 1);
        csr[s + r] = p >> BSHIFT;
    }
}

// ---------------------------------------------------------------------------
// per dst node: 8 lanes (one __half2 feature pair each) walk the CSR segment,
// gather hp[src] (L2-resident table), accumulate fp32, finalize + bias + out.
// [proven round 3: ~30us]
// ---------------------------------------------------------------------------
__global__ __launch_bounds__(256) void gather_out(const int* __restrict__ csr,
                                                  const int* __restrict__ off,
                                                  const int* __restrict__ hist,
                                                  const __half* __restrict__ hp,
                                                  const float* __restrict__ b,
                                                  float* __restrict__ out, int n) {
    const long long gid = (long long)blockIdx.x * 256 + threadIdx.x;
    const int d = (int)(gid >> 3);
    const int j2 = (int)(gid & 7);
    if (d >= n) return;

    const int base = off[d];
    const int deg = hist[d];
    const __half2* hpt = (const __half2*)hp;

    // self-loop contribution
    const __half2 sv = hpt[(size_t)d * 8 + j2];
    float ax = __low2float(sv), ay = __high2float(sv);

    int k = 0;
    for (; k + 4 <= deg; k += 4) {      // 4 independent gathers in flight
        const int s0 = csr[base + k + 0];
        const int s1 = csr[base + k + 1];
        const int s2 = csr[base + k + 2];
        const int s3 = csr[base + k + 3];
        const __half2 v0 = hpt[(size_t)s0 * 8 + j2];
        const __half2 v1 = hpt[(size_t)s1 * 8 + j2];
        const __half2 v2 = hpt[(size_t)s2 * 8 + j2];
        const __half2 v3 = hpt[(size_t)s3 * 8 + j2];
        ax += __low2float(v0) + __low2float(v1) + __low2float(v2) + __low2float(v3);
        ay += __high2float(v0) + __high2float(v1) + __high2float(v2) + __high2float(v3);
    }
    for (; k < deg; ++k) {
        const __half2 v = hpt[(size_t)csr[base + k] * 8 + j2];
        ax += __low2float(v);
        ay += __high2float(v);
    }

    const float di = rsqrtf((float)(deg + 1));
    float2 o;
    o.x = di * ax + b[2 * j2];
    o.y = di * ay + b[2 * j2 + 1];
    ((float2*)out)[(size_t)d * 8 + j2] = o;
}

// ---------------------------------------------------------------------------
// fallback path (proven atomic scatter) — only if guards fail
// ---------------------------------------------------------------------------
__global__ void hist_dst(const int* __restrict__ dst, int* __restrict__ hist, int E) {
    const int t = blockIdx.x * 256 + threadIdx.x;
    const int e0 = t * 4;
    if ((E & 3) == 0 && e0 + 3 < E) {
        const int4 d = *(const int4*)(dst + e0);
        atomicAdd(&hist[d.x], 1);
        atomicAdd(&hist[d.y], 1);
        atomicAdd(&hist[d.z], 1);
        atomicAdd(&hist[d.w], 1);
    } else {
        for (int e = e0; e < E && e < e0 + 4; ++e) atomicAdd(&hist[dst[e]], 1);
    }
}

__global__ __launch_bounds__(256) void scatter_f16(const int* __restrict__ ei,
                                                   const __half* __restrict__ hp,
                                                   __half2* __restrict__ acc, int E) {
    const long long gid = (long long)blockIdx.x * 256 + threadIdx.x;
    const int g = (int)(gid >> 3);
    const int j2 = (int)(gid & 7);
    const int e0 = g * 4;
    if (e0 >= E) return;

    int src[4], dst[4];
#pragma unroll
    for (int u = 0; u < 4; ++u) {
        const int e = e0 + u;
        src[u] = (e < E) ? ei[e] : -1;
        dst[u] = (e < E) ? ei[(size_t)E + e] : -1;
    }
    __half2 v[4];
#pragma unroll
    for (int u = 0; u < 4; ++u)
        if (src[u] >= 0) v[u] = ((const __half2*)(hp + (size_t)src[u] * OUT_DIM))[j2];
#pragma unroll
    for (int u = 0; u < 4; ++u)
        if (dst[u] >= 0) unsafeAtomicAdd(&acc[(size_t)dst[u] * 8 + j2], v[u]);
}

__global__ void finalize(const __half* __restrict__ acc, const __half* __restrict__ hp,
                         const int* __restrict__ hist, const float* __restrict__ b,
                         float* __restrict__ out, int n) {
    const int gid = blockIdx.x * 256 + threadIdx.x;
    if (gid >= n * OUT_DIM) return;
    const int i = gid >> 4;
    const int j = gid & 15;
    const float di = rsqrtf((float)(hist[i] + 1));
    out[gid] = di * (__half2float(acc[gid]) + __half2float(hp[gid])) + b[j];
}

// ---------------------------------------------------------------------------

extern "C" void kernel_launch(void* const* d_in, const int* in_sizes, int n_in,
                              void* d_out, int out_size, void* d_ws, size_t ws_size,
                              hipStream_t stream) {
    const float* x  = (const float*)d_in[0];
    const int*   ei = (const int*)d_in[1];   // int inputs delivered as int32
    const float* W  = (const float*)d_in[2];
    const float* b  = (const float*)d_in[3];
    float* out = (float*)d_out;

    const int n = in_sizes[0] / IN_DIM;   // 100000
    const int E = in_sizes[1] / 2;        // 3200000
    const int nbuck = (n + BNODES - 1) >> BSHIFT;

    // fast-path ws layout:
    // hp [n*16 f16] | hist [n] | off [n] | bbase[512] | bcur[512] | bcnt[512]
    // | bins [E] | csr [E]
    __half* hp    = (__half*)d_ws;
    int*    hist  = (int*)(hp + (size_t)n * OUT_DIM);
    int*    off   = hist + n;
    int*    bbase = off + n;
    int*    bcur  = bbase + MAXBUCK;
    int*    bcnt  = bcur + MAXBUCK;
    int*    bins  = bcnt + MAXBUCK;
    int*    csr   = bins + (size_t)E;

    const size_t need = (size_t)n * OUT_DIM * sizeof(__half)
                      + ((size_t)2 * n + 3 * MAXBUCK) * sizeof(int)
                      + 2 * (size_t)E * sizeof(int);

    if (ws_size >= need && nbuck <= MAXBUCK && n < (1 << 23)) {
        hipMemsetAsync(bcnt, 0, MAXBUCK * sizeof(int), stream);

        bcount<<<(E + BCOUNT_CHUNK - 1) / BCOUNT_CHUNK, 256, 0, stream>>>(ei + E, bcnt, E, nbuck);
        bucket_scan<<<1, 512, 0, stream>>>(bcnt, bbase, bcur, nbuck);
        bin_edges<<<(E + BIN_CHUNK - 1) / BIN_CHUNK, 256, 0, stream>>>(ei, bcur, bins, E, nbuck);
        bucket_sort<<<nbuck, 1024, 0, stream>>>(bins, bbase, bcur, csr, hist, off, n);
        gemm_wave<<<(n + 255) / 256, 256, 0, stream>>>(x, W, hist, hp, n);
        gather_out<<<(int)(((size_t)n * 8 + 255) / 256), 256, 0, stream>>>(csr, off, hist, hp, b, out, n);
    } else {
        // fallback: proven atomic-scatter path (~7.2 MB ws)
        __half* acc = (__half*)(hist + n);
        hipMemsetAsync(hist, 0, (size_t)n * sizeof(int), stream);
        hipMemsetAsync(acc, 0, (size_t)n * OUT_DIM * sizeof(__half), stream);

        hist_dst<<<(E + 1023) / 1024, 256, 0, stream>>>(ei + E, hist, E);
        gemm_xw<<<(n + TILE_ROWS - 1) / TILE_ROWS, 256, 0, stream>>>(x, W, hist, hp, n);
        const long long st = ((long long)(E + 3) / 4) * 8;
        scatter_f16<<<(int)((st + 255) / 256), 256, 0, stream>>>(ei, hp, (__half2*)acc, E);
        finalize<<<(n * OUT_DIM + 255) / 256, 256, 0, stream>>>(acc, hp, hist, b, out, n);
    }
}

// Round 10
// 401.680 us; speedup vs baseline: 1.1595x; 1.0662x over previous
//
#include <hip/hip_runtime.h>
#include <hip/hip_fp16.h>

#define IN_DIM 512
#define OUT_DIM 16
#define KC 32
#define TILE_ROWS 256

#define BSHIFT 8                 // 256 nodes per bucket
#define BNODES 256
#define MAXBUCK 512              // supports n <= 131072
#define BCOUNT_CHUNK 4096        // edges per bcount block
#define BIN_CHUNK 4096           // edges per binning block (16/thread, round-4 proven)

// ---------------------------------------------------------------------------
// hp(fp16) = rsqrt(deg) ⊙ (x @ W) — wave-private barrier-free + 4-way K-split.
// Block = 256 thr = 64 rows; wave w owns K-seg [128w,128w+128) + its own LDS
// slice (64x33). Per chunk (KC=32): store staged regs -> own slice, issue next
// chunk's loads, compute (wave-local lgkmcnt/vmcnt only — NO loop barriers).
// Grid 1563 blocks x 33.8KB LDS -> 4 blocks/CU = 16 waves/CU (fixes R9's
// 1.5-block/CU starvation) while keeping R9's no-lockstep streaming.
// Two barriers total, for the final cross-wave reduce.
// ---------------------------------------------------------------------------
__global__ __launch_bounds__(256) void gemm_hybrid(const float* __restrict__ x,
                                                   const float* __restrict__ W,
                                                   const int* __restrict__ hist,
                                                   __half* __restrict__ hp, int n) {
    __shared__ float xs[4 * 64 * (KC + 1)];       // 4 wave-private slices
    const int tid = threadIdx.x;
    const int lane = tid & 63;
    const int w = __builtin_amdgcn_readfirstlane(tid >> 6);  // wave's K-segment
    const int rbase = blockIdx.x * 64;
    const int myrow = rbase + lane;

    float* xw = xs + w * (64 * (KC + 1));          // this wave's slice
    // staging geometry: pass i, lane l -> row 8i+(l>>3), 16B col (l&7)*4
    const int srow = lane >> 3;
    const int scol = (lane & 7) << 2;
    const int kbase = w * 128;

    float4 stA[8], stB[8];

#define LOADC(buf, c)                                                          \
    {                                                                          \
        _Pragma("unroll")                                                      \
        for (int i = 0; i < 8; ++i) {                                          \
            const int rr = rbase + 8 * i + srow;                               \
            if (rr < n)                                                        \
                buf[i] = *(const float4*)(x + (size_t)rr * IN_DIM + kbase + (c) * KC + scol); \
            else                                                               \
                buf[i] = make_float4(0.f, 0.f, 0.f, 0.f);                      \
        }                                                                      \
    }

#define STOREC(buf)                                                            \
    {                                                                          \
        _Pragma("unroll")                                                      \
        for (int i = 0; i < 8; ++i) {                                          \
            float* d = xw + (8 * i + srow) * (KC + 1) + scol;                  \
            d[0] = buf[i].x; d[1] = buf[i].y; d[2] = buf[i].z; d[3] = buf[i].w; \
        }                                                                      \
    }

#define COMPUTEC(c)                                                            \
    {                                                                          \
        const float* xrow = xw + lane * (KC + 1);                              \
        const float* Wb = W + (size_t)(kbase + (c) * KC) * OUT_DIM;            \
        _Pragma("unroll 4")                                                    \
        for (int k = 0; k < KC; ++k) {                                         \
            const float xv = xrow[k];                                          \
            const float* wr = Wb + k * OUT_DIM;                                \
            const float4 w0 = *(const float4*)(wr + 0);                        \
            const float4 w1 = *(const float4*)(wr + 4);                        \
            const float4 w2 = *(const float4*)(wr + 8);                        \
            const float4 w3 = *(const float4*)(wr + 12);                       \
            acc[0]  += xv * w0.x; acc[1]  += xv * w0.y; acc[2]  += xv * w0.z; acc[3]  += xv * w0.w; \
            acc[4]  += xv * w1.x; acc[5]  += xv * w1.y; acc[6]  += xv * w1.z; acc[7]  += xv * w1.w; \
            acc[8]  += xv * w2.x; acc[9]  += xv * w2.y; acc[10] += xv * w2.z; acc[11] += xv * w2.w; \
            acc[12] += xv * w3.x; acc[13] += xv * w3.y; acc[14] += xv * w3.z; acc[15] += xv * w3.w; \
        }                                                                      \
    }

    float acc[OUT_DIM];
#pragma unroll
    for (int j = 0; j < OUT_DIM; ++j) acc[j] = 0.f;

    // 4 chunks of KC=32, register double-buffered, no barriers
    LOADC(stA, 0);
    STOREC(stA); LOADC(stB, 1); COMPUTEC(0);
    STOREC(stB); LOADC(stA, 2); COMPUTEC(1);
    STOREC(stA); LOADC(stB, 3); COMPUTEC(2);
    STOREC(stB);                COMPUTEC(3);

    // cross-wave reduce: waves 1..3 park partials (stride 17), wave 0 sums
    __syncthreads();                               // all slices consumed
    if (w > 0) {
        float* d = xs + (w - 1) * (64 * 17) + lane * 17;
#pragma unroll
        for (int j = 0; j < OUT_DIM; ++j) d[j] = acc[j];
    }
    __syncthreads();
    if (tid < 64 && myrow < n) {
        const float* p0 = xs + 0 * (64 * 17) + tid * 17;
        const float* p1 = xs + 1 * (64 * 17) + tid * 17;
        const float* p2 = xs + 2 * (64 * 17) + tid * 17;
        const float s = rsqrtf((float)(hist[myrow] + 1));
        __half2* op = (__half2*)(hp + (size_t)myrow * OUT_DIM);
#pragma unroll
        for (int j = 0; j < 8; ++j) {
            const float lo = acc[2 * j]     + p0[2 * j]     + p1[2 * j]     + p2[2 * j];
            const float hi = acc[2 * j + 1] + p0[2 * j + 1] + p1[2 * j + 1] + p2[2 * j + 1];
            op[j] = __floats2half2_rn(s * lo, s * hi);
        }
    }
#undef LOADC
#undef STOREC
#undef COMPUTEC
}

// ---------------------------------------------------------------------------
// fallback-path GEMM (proven): 256 rows/block, full K per thread
// ---------------------------------------------------------------------------
__global__ __launch_bounds__(256) void gemm_xw(const float* __restrict__ x,
                                               const float* __restrict__ W,
                                               const int* __restrict__ hist,
                                               __half* __restrict__ hp, int n) {
    __shared__ float xs[TILE_ROWS * (KC + 1)];
    const int tid = threadIdx.x;
    const int rbase = blockIdx.x * TILE_ROWS;
    const int myrow = rbase + tid;

    float acc[OUT_DIM];
#pragma unroll
    for (int j = 0; j < OUT_DIM; ++j) acc[j] = 0.f;

    for (int kc = 0; kc < IN_DIM; kc += KC) {
        __syncthreads();
#pragma unroll
        for (int i = 0; i < 8; ++i) {
            const int v = tid + 256 * i;
            const int r = v >> 3;
            const int c = (v & 7) << 2;
            if (rbase + r < n) {
                const float4 f = *(const float4*)(x + (size_t)(rbase + r) * IN_DIM + kc + c);
                float* d = xs + r * (KC + 1) + c;
                d[0] = f.x; d[1] = f.y; d[2] = f.z; d[3] = f.w;
            }
        }
        __syncthreads();

        const float* xrow = xs + tid * (KC + 1);
#pragma unroll 4
        for (int k = 0; k < KC; ++k) {
            const float xv = xrow[k];
            const float* wr = W + (size_t)(kc + k) * OUT_DIM;
            const float4 w0 = *(const float4*)(wr + 0);
            const float4 w1 = *(const float4*)(wr + 4);
            const float4 w2 = *(const float4*)(wr + 8);
            const float4 w3 = *(const float4*)(wr + 12);
            acc[0]  += xv * w0.x; acc[1]  += xv * w0.y; acc[2]  += xv * w0.z; acc[3]  += xv * w0.w;
            acc[4]  += xv * w1.x; acc[5]  += xv * w1.y; acc[6]  += xv * w1.z; acc[7]  += xv * w1.w;
            acc[8]  += xv * w2.x; acc[9]  += xv * w2.y; acc[10] += xv * w2.z; acc[11] += xv * w2.w;
            acc[12] += xv * w3.x; acc[13] += xv * w3.y; acc[14] += xv * w3.z; acc[15] += xv * w3.w;
        }
    }

    if (myrow < n) {
        const float s = rsqrtf((float)(hist[myrow] + 1));
        __half2* op = (__half2*)(hp + (size_t)myrow * OUT_DIM);
#pragma unroll
        for (int j = 0; j < 8; ++j)
            op[j] = __floats2half2_rn(s * acc[2 * j], s * acc[2 * j + 1]);
    }
}

// ---------------------------------------------------------------------------
// wave-0 exclusive scans over LDS arrays (lane-private spans -> shfl scan)
// ---------------------------------------------------------------------------
__device__ inline void scan512_excl(const int* src, int* dst, int lane) {
    int c[8], pre[8];
    int tot = 0;
#pragma unroll
    for (int k = 0; k < 8; ++k) { c[k] = src[lane * 8 + k]; pre[k] = tot; tot += c[k]; }
    int incl = tot;
#pragma unroll
    for (int d = 1; d < 64; d <<= 1) {
        const int u = __shfl_up(incl, d);
        if (lane >= d) incl += u;
    }
    const int excl = incl - tot;
#pragma unroll
    for (int k = 0; k < 8; ++k) dst[lane * 8 + k] = excl + pre[k];
}

__device__ inline void scan256_excl(const int* src, int* dst, int lane) {
    int c[4], pre[4];
    int tot = 0;
#pragma unroll
    for (int k = 0; k < 4; ++k) { c[k] = src[lane * 4 + k]; pre[k] = tot; tot += c[k]; }
    int incl = tot;
#pragma unroll
    for (int d = 1; d < 64; d <<= 1) {
        const int u = __shfl_up(incl, d);
        if (lane >= d) incl += u;
    }
    const int excl = incl - tot;
#pragma unroll
    for (int k = 0; k < 4; ++k) dst[lane * 4 + k] = excl + pre[k];
}

// ---------------------------------------------------------------------------
// per-bucket edge counts: LDS histogram per block, one global atomic/bucket
// ---------------------------------------------------------------------------
__global__ __launch_bounds__(256) void bcount(const int* __restrict__ dst,
                                              int* __restrict__ bcnt, int E, int nbuck) {
    __shared__ int lhist[MAXBUCK];
    const int tid = threadIdx.x;
    for (int i = tid; i < MAXBUCK; i += 256) lhist[i] = 0;
    __syncthreads();

    const int base = blockIdx.x * BCOUNT_CHUNK + tid * 16;
#pragma unroll
    for (int g = 0; g < 4; ++g) {
        const int e = base + g * 4;
        if (e + 3 < E) {
            const int4 d = *(const int4*)(dst + e);
            atomicAdd(&lhist[d.x >> BSHIFT], 1);
            atomicAdd(&lhist[d.y >> BSHIFT], 1);
            atomicAdd(&lhist[d.z >> BSHIFT], 1);
            atomicAdd(&lhist[d.w >> BSHIFT], 1);
        } else {
            for (int u = 0; u < 4; ++u)
                if (e + u < E) atomicAdd(&lhist[dst[e + u] >> BSHIFT], 1);
        }
    }
    __syncthreads();
    for (int i = tid; i < nbuck; i += 256)
        if (lhist[i] > 0) atomicAdd(&bcnt[i], lhist[i]);
}

// exclusive scan of bucket counts -> segment base + write cursor
__global__ __launch_bounds__(512) void bucket_scan(const int* __restrict__ bcnt,
                                                   int* __restrict__ bbase,
                                                   int* __restrict__ bcur, int nbuck) {
    __shared__ int sm[MAXBUCK];
    const int t = threadIdx.x;
    sm[t] = (t < nbuck) ? bcnt[t] : 0;
    __syncthreads();
    if (t < 64) scan512_excl(sm, sm, t);
    __syncthreads();
    bbase[t] = sm[t];
    bcur[t] = sm[t];
}

// ---------------------------------------------------------------------------
// bin edges by dst bucket (256 nodes/bucket), LDS-staged for coalesced output.
// bins[pos] = (src << 8) | (dst & 255), bucket-contiguous.  [round-4 proven]
// ---------------------------------------------------------------------------
__global__ __launch_bounds__(256) void bin_edges(const int* __restrict__ ei,
                                                 int* __restrict__ bcur,
                                                 int* __restrict__ bins,
                                                 int E, int nbuck) {
    __shared__ int lhist[MAXBUCK];
    __shared__ int lbase[MAXBUCK];
    __shared__ int gbase[MAXBUCK];
    __shared__ int stage[BIN_CHUNK];
    __shared__ short sbkt[BIN_CHUNK];

    const int tid = threadIdx.x;
    const int e0 = blockIdx.x * BIN_CHUNK;
    const int cnt = min(BIN_CHUNK, E - e0);

    for (int i = tid; i < MAXBUCK; i += 256) lhist[i] = 0;
    __syncthreads();

    int myb[16], myr[16], myp[16];
    const int base = e0 + tid * 16;
#pragma unroll
    for (int g = 0; g < 4; ++g) {
        const int e = base + g * 4;
        int ss[4], dd[4];
        if ((E & 3) == 0 && e + 3 < E) {
            const int4 s4 = *(const int4*)(ei + e);
            const int4 d4 = *(const int4*)(ei + (size_t)E + e);
            ss[0] = s4.x; ss[1] = s4.y; ss[2] = s4.z; ss[3] = s4.w;
            dd[0] = d4.x; dd[1] = d4.y; dd[2] = d4.z; dd[3] = d4.w;
        } else {
#pragma unroll
            for (int u = 0; u < 4; ++u) {
                const int idx = e + u;
                ss[u] = (idx < E) ? ei[idx] : -1;
                dd[u] = (idx < E) ? ei[(size_t)E + idx] : 0;
            }
        }
#pragma unroll
        for (int u = 0; u < 4; ++u) {
            const int j = g * 4 + u;
            if (ss[u] >= 0) {
                const int bk = dd[u] >> BSHIFT;
                myb[j] = bk;
                myp[j] = (ss[u] << BSHIFT) | (dd[u] & (BNODES - 1));
                myr[j] = atomicAdd(&lhist[bk], 1);
            } else {
                myb[j] = -1; myr[j] = 0; myp[j] = 0;
            }
        }
    }
    __syncthreads();

    if (tid < 64) scan512_excl(lhist, lbase, tid);     // counts -> local offsets
    for (int i = tid; i < nbuck; i += 256)
        if (lhist[i] > 0) gbase[i] = atomicAdd(&bcur[i], lhist[i]);
    __syncthreads();

#pragma unroll
    for (int j = 0; j < 16; ++j) {
        if (myb[j] >= 0) {
            const int p = lbase[myb[j]] + myr[j];
            stage[p] = myp[j];
            sbkt[p] = (short)myb[j];
        }
    }
    __syncthreads();

    for (int i = tid; i < cnt; i += 256) {
        const int bk = sbkt[i];
        bins[gbase[bk] + (i - lbase[bk])] = stage[i];
    }
}

// ---------------------------------------------------------------------------
// per-bucket counting sort -> node-sorted csr. 1024 threads/block (8 serial
// iters/thread): proven ~25us in round 9.
// ---------------------------------------------------------------------------
__global__ __launch_bounds__(1024) void bucket_sort(const int* __restrict__ bins,
                                                    const int* __restrict__ bbase,
                                                    const int* __restrict__ bcur,
                                                    int* __restrict__ csr,
                                                    int* __restrict__ hist,
                                                    int* __restrict__ off, int n) {
    __shared__ int nhist[BNODES];
    __shared__ int nbase[BNODES];
    __shared__ int ncur[BNODES];
    const int tid = threadIdx.x;
    const int b = blockIdx.x;
    const int s = bbase[b];
    const int e = bcur[b];

    if (tid < BNODES) nhist[tid] = 0;
    __syncthreads();
    for (int i = s + tid; i < e; i += 1024)
        atomicAdd(&nhist[bins[i] & (BNODES - 1)], 1);
    __syncthreads();
    if (tid < 64) scan256_excl(nhist, nbase, tid);
    __syncthreads();

    if (tid < BNODES) {
        const int node = (b << BSHIFT) + tid;
        if (node < n) {
            hist[node] = nhist[tid];
            off[node] = s + nbase[tid];
        }
        ncur[tid] = nbase[tid];
    }
    __syncthreads();

    for (int i = s + tid; i < e; i += 1024) {
        const int p = bins[i];                       // L2 hit (2nd read)
        const int r = atomicAdd(&ncur[p & (BNODES - 1)], 1);
        csr[s + r] = p >> BSHIFT;
    }
}

// ---------------------------------------------------------------------------
// per dst node: 8 lanes (one __half2 feature pair each) walk the CSR segment,
// gather hp[src] (L2-resident table), accumulate fp32, finalize + bias + out.
// [proven round 3: ~30us]
// ---------------------------------------------------------------------------
__global__ __launch_bounds__(256) void gather_out(const int* __restrict__ csr,
                                                  const int* __restrict__ off,
                                                  const int* __restrict__ hist,
                                                  const __half* __restrict__ hp,
                                                  const float* __restrict__ b,
                                                  float* __restrict__ out, int n) {
    const long long gid = (long long)blockIdx.x * 256 + threadIdx.x;
    const int d = (int)(gid >> 3);
    const int j2 = (int)(gid & 7);
    if (d >= n) return;

    const int base = off[d];
    const int deg = hist[d];
    const __half2* hpt = (const __half2*)hp;

    // self-loop contribution
    const __half2 sv = hpt[(size_t)d * 8 + j2];
    float ax = __low2float(sv), ay = __high2float(sv);

    int k = 0;
    for (; k + 4 <= deg; k += 4) {      // 4 independent gathers in flight
        const int s0 = csr[base + k + 0];
        const int s1 = csr[base + k + 1];
        const int s2 = csr[base + k + 2];
        const int s3 = csr[base + k + 3];
        const __half2 v0 = hpt[(size_t)s0 * 8 + j2];
        const __half2 v1 = hpt[(size_t)s1 * 8 + j2];
        const __half2 v2 = hpt[(size_t)s2 * 8 + j2];
        const __half2 v3 = hpt[(size_t)s3 * 8 + j2];
        ax += __low2float(v0) + __low2float(v1) + __low2float(v2) + __low2float(v3);
        ay += __high2float(v0) + __high2float(v1) + __high2float(v2) + __high2float(v3);
    }
    for (; k < deg; ++k) {
        const __half2 v = hpt[(size_t)csr[base + k] * 8 + j2];
        ax += __low2float(v);
        ay += __high2float(v);
    }

    const float di = rsqrtf((float)(deg + 1));
    float2 o;
    o.x = di * ax + b[2 * j2];
    o.y = di * ay + b[2 * j2 + 1];
    ((float2*)out)[(size_t)d * 8 + j2] = o;
}

// ---------------------------------------------------------------------------
// fallback path (proven atomic scatter) — only if guards fail
// ---------------------------------------------------------------------------
__global__ void hist_dst(const int* __restrict__ dst, int* __restrict__ hist, int E) {
    const int t = blockIdx.x * 256 + threadIdx.x;
    const int e0 = t * 4;
    if ((E & 3) == 0 && e0 + 3 < E) {
        const int4 d = *(const int4*)(dst + e0);
        atomicAdd(&hist[d.x], 1);
        atomicAdd(&hist[d.y], 1);
        atomicAdd(&hist[d.z], 1);
        atomicAdd(&hist[d.w], 1);
    } else {
        for (int e = e0; e < E && e < e0 + 4; ++e) atomicAdd(&hist[dst[e]], 1);
    }
}

__global__ __launch_bounds__(256) void scatter_f16(const int* __restrict__ ei,
                                                   const __half* __restrict__ hp,
                                                   __half2* __restrict__ acc, int E) {
    const long long gid = (long long)blockIdx.x * 256 + threadIdx.x;
    const int g = (int)(gid >> 3);
    const int j2 = (int)(gid & 7);
    const int e0 = g * 4;
    if (e0 >= E) return;

    int src[4], dst[4];
#pragma unroll
    for (int u = 0; u < 4; ++u) {
        const int e = e0 + u;
        src[u] = (e < E) ? ei[e] : -1;
        dst[u] = (e < E) ? ei[(size_t)E + e] : -1;
    }
    __half2 v[4];
#pragma unroll
    for (int u = 0; u < 4; ++u)
        if (src[u] >= 0) v[u] = ((const __half2*)(hp + (size_t)src[u] * OUT_DIM))[j2];
#pragma unroll
    for (int u = 0; u < 4; ++u)
        if (dst[u] >= 0) unsafeAtomicAdd(&acc[(size_t)dst[u] * 8 + j2], v[u]);
}

__global__ void finalize(const __half* __restrict__ acc, const __half* __restrict__ hp,
                         const int* __restrict__ hist, const float* __restrict__ b,
                         float* __restrict__ out, int n) {
    const int gid = blockIdx.x * 256 + threadIdx.x;
    if (gid >= n * OUT_DIM) return;
    const int i = gid >> 4;
    const int j = gid & 15;
    const float di = rsqrtf((float)(hist[i] + 1));
    out[gid] = di * (__half2float(acc[gid]) + __half2float(hp[gid])) + b[j];
}

// ---------------------------------------------------------------------------

extern "C" void kernel_launch(void* const* d_in, const int* in_sizes, int n_in,
                              void* d_out, int out_size, void* d_ws, size_t ws_size,
                              hipStream_t stream) {
    const float* x  = (const float*)d_in[0];
    const int*   ei = (const int*)d_in[1];   // int inputs delivered as int32
    const float* W  = (const float*)d_in[2];
    const float* b  = (const float*)d_in[3];
    float* out = (float*)d_out;

    const int n = in_sizes[0] / IN_DIM;   // 100000
    const int E = in_sizes[1] / 2;        // 3200000
    const int nbuck = (n + BNODES - 1) >> BSHIFT;

    // fast-path ws layout:
    // hp [n*16 f16] | hist [n] | off [n] | bbase[512] | bcur[512] | bcnt[512]
    // | bins [E] | csr [E]
    __half* hp    = (__half*)d_ws;
    int*    hist  = (int*)(hp + (size_t)n * OUT_DIM);
    int*    off   = hist + n;
    int*    bbase = off + n;
    int*    bcur  = bbase + MAXBUCK;
    int*    bcnt  = bcur + MAXBUCK;
    int*    bins  = bcnt + MAXBUCK;
    int*    csr   = bins + (size_t)E;

    const size_t need = (size_t)n * OUT_DIM * sizeof(__half)
                      + ((size_t)2 * n + 3 * MAXBUCK) * sizeof(int)
                      + 2 * (size_t)E * sizeof(int);

    if (ws_size >= need && nbuck <= MAXBUCK && n < (1 << 23)) {
        hipMemsetAsync(bcnt, 0, MAXBUCK * sizeof(int), stream);

        bcount<<<(E + BCOUNT_CHUNK - 1) / BCOUNT_CHUNK, 256, 0, stream>>>(ei + E, bcnt, E, nbuck);
        bucket_scan<<<1, 512, 0, stream>>>(bcnt, bbase, bcur, nbuck);
        bin_edges<<<(E + BIN_CHUNK - 1) / BIN_CHUNK, 256, 0, stream>>>(ei, bcur, bins, E, nbuck);
        bucket_sort<<<nbuck, 1024, 0, stream>>>(bins, bbase, bcur, csr, hist, off, n);
        gemm_hybrid<<<(n + 63) / 64, 256, 0, stream>>>(x, W, hist, hp, n);
        gather_out<<<(int)(((size_t)n * 8 + 255) / 256), 256, 0, stream>>>(csr, off, hist, hp, b, out, n);
    } else {
        // fallback: proven atomic-scatter path (~7.2 MB ws)
        __half* acc = (__half*)(hist + n);
        hipMemsetAsync(hist, 0, (size_t)n * sizeof(int), stream);
        hipMemsetAsync(acc, 0, (size_t)n * OUT_DIM * sizeof(__half), stream);

        hist_dst<<<(E + 1023) / 1024, 256, 0, stream>>>(ei + E, hist, E);
        gemm_xw<<<(n + TILE_ROWS - 1) / TILE_ROWS, 256, 0, stream>>>(x, W, hist, hp, n);
        const long long st = ((long long)(E + 3) / 4) * 8;
        scatter_f16<<<(int)((st + 255) / 256), 256, 0, stream>>>(ei, hp, (__half2*)acc, E);
        finalize<<<(n * OUT_DIM + 255) / 256, 256, 0, stream>>>(acc, hp, hist, b, out, n);
    }
}